// Round 4
// baseline (891.264 us; speedup 1.0000x reference)
//
#include <hip/hip_runtime.h>
#include <math.h>

#define BB 8
#define PP 5
#define QQ 75
#define CC 640
#define HW 49
#define NIMG_Q (BB*QQ)     // 600
#define NIMG_S (BB*PP)     // 40
#define NPROB  (BB*QQ*PP)  // 3000
#define TEMP 12.5f

// workspace layout (float offsets); total ~769K floats ~ 3.1 MB
#define OFF_SGAP   0
#define OFF_QGAP   (OFF_SGAP  + NIMG_S*CC)
#define OFF_SMEAN  (OFF_QGAP  + NIMG_Q*CC)
#define OFF_SINV   (OFF_SMEAN + NIMG_S*HW)
#define OFF_QMEAN  (OFF_SINV  + NIMG_S*HW)
#define OFF_QINV   (OFF_QMEAN + NIMG_Q*HW)
#define OFF_MARGA  (OFF_QINV  + NIMG_Q*HW)
#define OFF_MARGB  (OFF_MARGA + NPROB*HW)
#define OFF_LOGITS (OFF_MARGB + NPROB*HW)

__device__ __forceinline__ float wsum64(float v) {
#pragma unroll
    for (int off = 32; off > 0; off >>= 1) v += __shfl_xor(v, off, 64);
    return v;
}

__device__ __forceinline__ float rlf(float x, int l) {
    return __int_as_float(__builtin_amdgcn_readlane(__float_as_int(x), l));
}

// ---------------- Kernel 1: support-image stats ----------------
// grid = 40, block = 256 (4 waves)
__global__ __launch_bounds__(256) void sup_stats_kernel(const float* __restrict__ sup,
                                                        float* __restrict__ ws) {
    int img = blockIdx.x;
    int tid = threadIdx.x;
    int lane = tid & 63;
    int wv = tid >> 6;
    const float* X = sup + (size_t)img * CC * HW;
    float* gap = ws + OFF_SGAP + img * CC;
    float* cmean = ws + OFF_SMEAN + img * HW;
    float* cinv = ws + OFF_SINV + img * HW;

    __shared__ float cs_p[4][52], sq_p[4][52];
    float cs = 0.f, sq = 0.f;
    if (lane < HW) {
        for (int c = wv * 160; c < wv * 160 + 160; c++) {
            float v = X[c * HW + lane];
            cs += v;
            sq = fmaf(v, v, sq);
        }
    }
    if (lane < 52) {
        cs_p[wv][lane] = (lane < HW) ? cs : 0.f;
        sq_p[wv][lane] = (lane < HW) ? sq : 0.f;
    }
    __syncthreads();
    if (wv == 0 && lane < HW) {
        float c4 = cs_p[0][lane] + cs_p[1][lane] + cs_p[2][lane] + cs_p[3][lane];
        float s4 = sq_p[0][lane] + sq_p[1][lane] + sq_p[2][lane] + sq_p[3][lane];
        float mu = c4 * (1.0f / CC);
        float nsq = fmaxf(s4 - c4 * c4 * (1.0f / CC), 0.f);
        cmean[lane] = mu;
        cinv[lane] = 1.0f / fmaxf(sqrtf(nsq), 1e-8f);
    }
    for (int c = tid; c < CC; c += 256) {
        float s = 0.f;
        for (int m = 0; m < HW; m++) s += X[c * HW + m];
        gap[c] = s * (1.0f / HW);
    }
}

// ---------------- Kernel 2: query stats + marga fused ----------------
// grid = 600, block = 256. Reads each query image once for stats AND the
// 5 w1 marginal dots (previously two kernels = two 75 MB passes).
__global__ __launch_bounds__(256) void qry_kernel(const float* __restrict__ qry,
                                                  float* __restrict__ ws) {
    int img = blockIdx.x;            // = bq
    int b = img / QQ;
    int tid = threadIdx.x;
    int lane = tid & 63;
    int wv = tid >> 6;
    const float* X = qry + (size_t)img * CC * HW;
    const float* sg = ws + OFF_SGAP + b * PP * CC;
    float* gap = ws + OFF_QGAP + img * CC;
    float* cmean = ws + OFF_QMEAN + img * HW;
    float* cinv = ws + OFF_QINV + img * HW;

    __shared__ float cs_p[4][52], sq_p[4][52];
    __shared__ float part[4][PP][52];
    float cs = 0.f, sq = 0.f;
    float acc[PP] = {0.f, 0.f, 0.f, 0.f, 0.f};
    if (lane < HW) {
        for (int c = wv * 160; c < wv * 160 + 160; c++) {
            float v = X[c * HW + lane];
            cs += v;
            sq = fmaf(v, v, sq);
#pragma unroll
            for (int p = 0; p < PP; p++) acc[p] = fmaf(v, sg[p * CC + c], acc[p]);
        }
    }
    if (lane < 52) {
        cs_p[wv][lane] = (lane < HW) ? cs : 0.f;
        sq_p[wv][lane] = (lane < HW) ? sq : 0.f;
#pragma unroll
        for (int p = 0; p < PP; p++) part[wv][p][lane] = (lane < HW) ? acc[p] : 0.f;
    }
    __syncthreads();
    if (wv == 0) {
        if (lane < HW) {
            float c4 = cs_p[0][lane] + cs_p[1][lane] + cs_p[2][lane] + cs_p[3][lane];
            float s4 = sq_p[0][lane] + sq_p[1][lane] + sq_p[2][lane] + sq_p[3][lane];
            float mu = c4 * (1.0f / CC);
            float nsq = fmaxf(s4 - c4 * c4 * (1.0f / CC), 0.f);
            cmean[lane] = mu;
            cinv[lane] = 1.0f / fmaxf(sqrtf(nsq), 1e-8f);
        }
#pragma unroll
        for (int p = 0; p < PP; p++) {
            float a = 0.f;
            if (lane < 52)
                a = part[0][p][lane] + part[1][p][lane] + part[2][p][lane] + part[3][p][lane];
            float w = (lane < HW) ? (fmaxf(a, 0.f) + 1.01e-3f) : 0.f;
            float s = wsum64(w);
            if (lane < HW) ws[OFF_MARGA + (img * PP + p) * HW + lane] = w / s;
        }
    }
    // pass B: GAP (re-reads X from L2 -- image is hot)
    for (int c = tid; c < CC; c += 256) {
        float s = 0.f;
        for (int m = 0; m < HW; m++) s += X[c * HW + m];
        gap[c] = s * (1.0f / HW);
    }
}

// ---------------- Kernel 3: col marginals b (support side, w2) ----------------
// grid = 200, block = 256 (4 waves x 160 channels); 15 q's per block
__global__ __launch_bounds__(256) void margb_kernel(const float* __restrict__ sup,
                                                    float* __restrict__ ws) {
    int id = blockIdx.x;
    int qc = id % 5;
    int bp = id / 5;
    int b = bp / PP;
    int p = bp % PP;
    int tid = threadIdx.x;
    int lane = tid & 63;
    int wv = tid >> 6;
    const float* X = sup + (size_t)bp * CC * HW;
    const float* qg = ws + OFF_QGAP + (b * QQ + qc * 15) * CC;
    float acc[15];
#pragma unroll
    for (int i = 0; i < 15; i++) acc[i] = 0.f;
    if (lane < HW) {
        for (int c = wv * 160; c < wv * 160 + 160; c++) {
            float sv = X[c * HW + lane];
#pragma unroll
            for (int qq = 0; qq < 15; qq++)
                acc[qq] = fmaf(sv, qg[qq * CC + c], acc[qq]);
        }
    }
    __shared__ float part[4][15][52];
    if (lane < 52) {
#pragma unroll
        for (int qq = 0; qq < 15; qq++) part[wv][qq][lane] = (lane < HW) ? acc[qq] : 0.f;
    }
    __syncthreads();
    if (wv == 0) {
#pragma unroll
        for (int qq = 0; qq < 15; qq++) {
            float a = 0.f;
            if (lane < 52)
                a = part[0][qq][lane] + part[1][qq][lane] + part[2][qq][lane] + part[3][qq][lane];
            int q = qc * 15 + qq;
            float w = (lane < HW) ? (fmaxf(a, 0.f) + 1.01e-3f) : 0.f;
            float s = wsum64(w);
            if (lane < HW) ws[OFF_MARGB + ((b * QQ + q) * PP + p) * HW + lane] = w / s;
        }
    }
}

// ---------------- Kernel 4: fused S-GEMM + Sinkhorn + logit ----------------
// K lives in AGPRs, pinned by inline asm ("a" constraints) -- the compiler's
// occupancy heuristic spilled every C++-level formulation (R1-R3: VGPR=80-84,
// WRITE_SIZE=95MB scratch). u/v broadcast via v_readlane (VALU), so the
// Sinkhorn loop touches NO memory at all.
#define AGPR_W(av, x) asm volatile("v_accvgpr_write_b32 %0, %1" : "=a"(av) : "v"(x))
#define AGPR_R(x, av) asm volatile("v_accvgpr_read_b32 %0, %1" : "=v"(x) : "a"(av))

#define KL(X) X(0) X(1) X(2) X(3) X(4) X(5) X(6) X(7) X(8) X(9) X(10) X(11) \
    X(12) X(13) X(14) X(15) X(16) X(17) X(18) X(19) X(20) X(21) X(22) X(23) \
    X(24) X(25) X(26) X(27) X(28) X(29) X(30) X(31) X(32) X(33) X(34) X(35) \
    X(36) X(37) X(38) X(39) X(40) X(41) X(42) X(43) X(44) X(45) X(46) X(47) X(48)

__global__ __launch_bounds__(256)
__attribute__((amdgpu_waves_per_eu(3, 3)))
void emd_kernel(const float* __restrict__ sup,
                const float* __restrict__ qry,
                float* __restrict__ ws) {
    __shared__ __align__(16) float AB[2][32][64];   // 16 KB staging; S_lds aliases it
    float (*S_lds)[53] = (float (*)[53])(&AB[0][0][0]);  // 50*53=2650 <= 4096 floats

    int prob = blockIdx.x;
    int p = prob % PP;
    int bq = prob / PP;
    int b = bq / QQ;
    int tid = threadIdx.x;
    int lane = tid & 63;
    int wv = tid >> 6;
    int sw = prob & 3;
    int tyc = tid / 13;
    int txc = tid - tyc * 13;
    bool active = tid < 169;

    const float* Xq = qry + (size_t)bq * CC * HW;
    const float* Xs = sup + (size_t)(b * PP + p) * CC * HW;

    float qm = 0.f, qi = 0.f, sm = 0.f, si = 0.f;
    if (lane < HW) {
        qm = ws[OFF_QMEAN + bq * HW + lane];
        qi = ws[OFF_QINV + bq * HW + lane];
        sm = ws[OFF_SMEAN + (b * PP + p) * HW + lane];
        si = ws[OFF_SINV + (b * PP + p) * HW + lane];
    }

    float acc[4][4];
#pragma unroll
    for (int i = 0; i < 4; i++)
#pragma unroll
        for (int j = 0; j < 4; j++) acc[i][j] = 0.f;

    for (int c0 = 0; c0 < CC; c0 += 32) {
        __syncthreads();
        for (int cl = wv; cl < 32; cl += 4) {
            int c = c0 + cl;
            float av = 0.f, bv = 0.f;
            if (lane < HW) {
                av = (Xq[c * HW + lane] - qm) * qi;
                bv = (Xs[c * HW + lane] - sm) * si;
            }
            AB[0][cl][lane] = av;
            AB[1][cl][lane] = bv;
        }
        __syncthreads();
        if (active) {
#pragma unroll
            for (int cl = 0; cl < 32; cl++) {
                float4 a4 = *(const float4*)&AB[0][cl][4 * tyc];
                float4 b4 = *(const float4*)&AB[1][cl][4 * txc];
                float av[4] = {a4.x, a4.y, a4.z, a4.w};
                float bv[4] = {b4.x, b4.y, b4.z, b4.w};
#pragma unroll
                for (int i = 0; i < 4; i++)
#pragma unroll
                    for (int j = 0; j < 4; j++) acc[i][j] = fmaf(av[i], bv[j], acc[i][j]);
            }
        }
    }

    __syncthreads();   // staging buffers dead; safe to overwrite with S
    if (active) {
#pragma unroll
        for (int i = 0; i < 4; i++) {
#pragma unroll
            for (int j = 0; j < 4; j++) {
                int m = 4 * tyc + i, n = 4 * txc + j;
                if (m < HW && n < HW) S_lds[m][n] = acc[i][j];
            }
        }
    }
    __syncthreads();
    if (wv != sw) return;  // one wave runs Sinkhorn

    float am = 0.f, bm = 0.f;
    if (lane < HW) {
        am = ws[OFF_MARGA + prob * HW + lane];
        bm = ws[OFF_MARGB + prob * HW + lane];
    }
    int lr = (lane < HW) ? lane : 0;

    // K = exp((S-1)/eps) = exp(20S-20); row lr -> kr#, column lr -> kt#, in AGPRs.
#define KD(n) float kr##n, kt##n;
    KL(KD)
#undef KD
#define KI(n) { float a_ = __expf(fmaf(20.f, S_lds[lr][n], -20.f));         \
                float b_ = __expf(fmaf(20.f, S_lds[n][lr], -20.f));         \
                AGPR_W(kr##n, a_); AGPR_W(kt##n, b_); }
    KL(KI)
#undef KI

    float vv = (lane < HW) ? 1.f : 0.f;
    float uu = 0.f;

#pragma unroll 1
    for (int it = 0; it < 100; it++) {
        // u = a / (K v): t_m = sum_n kr_n * v_n (v broadcast via readlane)
        float a4[4] = {0.f, 0.f, 0.f, 0.f};
#define UM(n) { float kv; AGPR_R(kv, kr##n);                                \
                a4[(n) & 3] = fmaf(rlf(vv, (n)), kv, a4[(n) & 3]); }
        KL(UM)
#undef UM
        float t = (a4[0] + a4[1]) + (a4[2] + a4[3]);
        uu = am * __builtin_amdgcn_rcpf(t);
        // v = b / (K^T u): s_n = sum_m kt_m * u_m
        float b4[4] = {0.f, 0.f, 0.f, 0.f};
#define VM(n) { float kv; AGPR_R(kv, kt##n);                                \
                b4[(n) & 3] = fmaf(rlf(uu, (n)), kv, b4[(n) & 3]); }
        KL(VM)
#undef VM
        float s = (b4[0] + b4[1]) + (b4[2] + b4[3]);
        vv = bm * __builtin_amdgcn_rcpf(s);
    }

    // logit = T * sum_{m,n} S_mn * u_m K_mn v_n
    float ssum = 0.f;
#define FS(n) { float kv; AGPR_R(kv, kr##n);                                \
                ssum = fmaf(S_lds[lr][n] * kv, rlf(vv, (n)), ssum); }
    KL(FS)
#undef FS
    float contrib = (lane < HW) ? (uu * ssum) : 0.f;
    float tot = wsum64(contrib);
    if (lane == 0) ws[OFF_LOGITS + prob] = TEMP * tot;
}

// ---------------- Kernel 5: cross-entropy loss ----------------
// grid = 1, block = 640
__global__ __launch_bounds__(640) void loss_kernel(const float* __restrict__ ws,
                                                   const int* __restrict__ qy,
                                                   float* __restrict__ out) {
    int tid = threadIdx.x;
    float val = 0.f;
    if (tid < NIMG_Q) {
        const float* lg = ws + OFF_LOGITS + tid * PP;
        float l[PP];
        float mx = -1e30f;
#pragma unroll
        for (int p = 0; p < PP; p++) {
            l[p] = lg[p];
            mx = fmaxf(mx, l[p]);
        }
        float se = 0.f;
#pragma unroll
        for (int p = 0; p < PP; p++) se += __expf(l[p] - mx);
        float lse = mx + logf(se);
        int lab = qy[tid];
        val = -(l[lab] - lse);
    }
    __shared__ float red[16];
    float s = wsum64(val);
    if ((tid & 63) == 0) red[tid >> 6] = s;
    __syncthreads();
    if (tid == 0) {
        float tot = 0.f;
#pragma unroll
        for (int w = 0; w < 10; w++) tot += red[w];
        out[0] = tot * (1.0f / NIMG_Q);
    }
}

extern "C" void kernel_launch(void* const* d_in, const int* in_sizes, int n_in,
                              void* d_out, int out_size, void* d_ws, size_t ws_size,
                              hipStream_t stream) {
    const float* sup = (const float*)d_in[0];   // support_xf [8,5,640,7,7]
    const float* qry = (const float*)d_in[1];   // query_xf   [8,75,640,7,7]
    const int* qy = (const int*)d_in[3];        // query_y    [8,75]
    float* ws = (float*)d_ws;
    float* out = (float*)d_out;

    sup_stats_kernel<<<NIMG_S, 256, 0, stream>>>(sup, ws);
    qry_kernel<<<NIMG_Q, 256, 0, stream>>>(qry, ws);
    margb_kernel<<<NIMG_S * 5, 256, 0, stream>>>(sup, ws);
    emd_kernel<<<NPROB, 256, 0, stream>>>(sup, qry, ws);
    loss_kernel<<<1, 640, 0, stream>>>(ws, qy, out);
}

// Round 5
// 628.042 us; speedup vs baseline: 1.4191x; 1.4191x over previous
//
#include <hip/hip_runtime.h>
#include <math.h>

#define BB 8
#define PP 5
#define QQ 75
#define CC 640
#define HW 49
#define HW2 (HW*HW)        // 2401
#define NIMG_Q (BB*QQ)     // 600
#define NIMG_S (BB*PP)     // 40
#define NPROB  (BB*QQ*PP)  // 3000
#define TEMP 12.5f

// workspace layout (float offsets); total ~15.2M floats ~ 61 MB
#define OFF_SGAP   0
#define OFF_QGAP   (OFF_SGAP  + NIMG_S*CC)
#define OFF_SMEAN  (OFF_QGAP  + NIMG_Q*CC)
#define OFF_SINV   (OFF_SMEAN + NIMG_S*HW)
#define OFF_QMEAN  (OFF_SINV  + NIMG_S*HW)
#define OFF_QINV   (OFF_QMEAN + NIMG_Q*HW)
#define OFF_MARGA  (OFF_QINV  + NIMG_Q*HW)
#define OFF_MARGB  (OFF_MARGA + NPROB*HW)
#define OFF_K      (OFF_MARGB + NPROB*HW)
#define OFF_KT     (OFF_K     + NPROB*HW2)
#define OFF_LOGITS (OFF_KT    + NPROB*HW2)

__device__ __forceinline__ float wsum64(float v) {
#pragma unroll
    for (int off = 32; off > 0; off >>= 1) v += __shfl_xor(v, off, 64);
    return v;
}

__device__ __forceinline__ float rlf(float x, int l) {
    return __int_as_float(__builtin_amdgcn_readlane(__float_as_int(x), l));
}

// ---------------- Kernel 1: support-image stats ----------------
// grid = 40, block = 256 (4 waves)
__global__ __launch_bounds__(256) void sup_stats_kernel(const float* __restrict__ sup,
                                                        float* __restrict__ ws) {
    int img = blockIdx.x;
    int tid = threadIdx.x;
    int lane = tid & 63;
    int wv = tid >> 6;
    const float* X = sup + (size_t)img * CC * HW;
    float* gap = ws + OFF_SGAP + img * CC;
    float* cmean = ws + OFF_SMEAN + img * HW;
    float* cinv = ws + OFF_SINV + img * HW;

    __shared__ float cs_p[4][52], sq_p[4][52];
    float cs = 0.f, sq = 0.f;
    if (lane < HW) {
        for (int c = wv * 160; c < wv * 160 + 160; c++) {
            float v = X[c * HW + lane];
            cs += v;
            sq = fmaf(v, v, sq);
        }
    }
    if (lane < 52) {
        cs_p[wv][lane] = (lane < HW) ? cs : 0.f;
        sq_p[wv][lane] = (lane < HW) ? sq : 0.f;
    }
    __syncthreads();
    if (wv == 0 && lane < HW) {
        float c4 = cs_p[0][lane] + cs_p[1][lane] + cs_p[2][lane] + cs_p[3][lane];
        float s4 = sq_p[0][lane] + sq_p[1][lane] + sq_p[2][lane] + sq_p[3][lane];
        float mu = c4 * (1.0f / CC);
        float nsq = fmaxf(s4 - c4 * c4 * (1.0f / CC), 0.f);
        cmean[lane] = mu;
        cinv[lane] = 1.0f / fmaxf(sqrtf(nsq), 1e-8f);
    }
    for (int c = tid; c < CC; c += 256) {
        float s = 0.f;
        for (int m = 0; m < HW; m++) s += X[c * HW + m];
        gap[c] = s * (1.0f / HW);
    }
}

// ---------------- Kernel 2: query stats + marga fused ----------------
__global__ __launch_bounds__(256) void qry_kernel(const float* __restrict__ qry,
                                                  float* __restrict__ ws) {
    int img = blockIdx.x;            // = bq
    int b = img / QQ;
    int tid = threadIdx.x;
    int lane = tid & 63;
    int wv = tid >> 6;
    const float* X = qry + (size_t)img * CC * HW;
    const float* sg = ws + OFF_SGAP + b * PP * CC;
    float* gap = ws + OFF_QGAP + img * CC;
    float* cmean = ws + OFF_QMEAN + img * HW;
    float* cinv = ws + OFF_QINV + img * HW;

    __shared__ float cs_p[4][52], sq_p[4][52];
    __shared__ float part[4][PP][52];
    float cs = 0.f, sq = 0.f;
    float acc[PP] = {0.f, 0.f, 0.f, 0.f, 0.f};
    if (lane < HW) {
        for (int c = wv * 160; c < wv * 160 + 160; c++) {
            float v = X[c * HW + lane];
            cs += v;
            sq = fmaf(v, v, sq);
#pragma unroll
            for (int p = 0; p < PP; p++) acc[p] = fmaf(v, sg[p * CC + c], acc[p]);
        }
    }
    if (lane < 52) {
        cs_p[wv][lane] = (lane < HW) ? cs : 0.f;
        sq_p[wv][lane] = (lane < HW) ? sq : 0.f;
#pragma unroll
        for (int p = 0; p < PP; p++) part[wv][p][lane] = (lane < HW) ? acc[p] : 0.f;
    }
    __syncthreads();
    if (wv == 0) {
        if (lane < HW) {
            float c4 = cs_p[0][lane] + cs_p[1][lane] + cs_p[2][lane] + cs_p[3][lane];
            float s4 = sq_p[0][lane] + sq_p[1][lane] + sq_p[2][lane] + sq_p[3][lane];
            float mu = c4 * (1.0f / CC);
            float nsq = fmaxf(s4 - c4 * c4 * (1.0f / CC), 0.f);
            cmean[lane] = mu;
            cinv[lane] = 1.0f / fmaxf(sqrtf(nsq), 1e-8f);
        }
#pragma unroll
        for (int p = 0; p < PP; p++) {
            float a = 0.f;
            if (lane < 52)
                a = part[0][p][lane] + part[1][p][lane] + part[2][p][lane] + part[3][p][lane];
            float w = (lane < HW) ? (fmaxf(a, 0.f) + 1.01e-3f) : 0.f;
            float s = wsum64(w);
            if (lane < HW) ws[OFF_MARGA + (img * PP + p) * HW + lane] = w / s;
        }
    }
    for (int c = tid; c < CC; c += 256) {
        float s = 0.f;
        for (int m = 0; m < HW; m++) s += X[c * HW + m];
        gap[c] = s * (1.0f / HW);
    }
}

// ---------------- Kernel 3: col marginals b (support side, w2) ----------------
__global__ __launch_bounds__(256) void margb_kernel(const float* __restrict__ sup,
                                                    float* __restrict__ ws) {
    int id = blockIdx.x;
    int qc = id % 5;
    int bp = id / 5;
    int b = bp / PP;
    int p = bp % PP;
    int tid = threadIdx.x;
    int lane = tid & 63;
    int wv = tid >> 6;
    const float* X = sup + (size_t)bp * CC * HW;
    const float* qg = ws + OFF_QGAP + (b * QQ + qc * 15) * CC;
    float acc[15];
#pragma unroll
    for (int i = 0; i < 15; i++) acc[i] = 0.f;
    if (lane < HW) {
        for (int c = wv * 160; c < wv * 160 + 160; c++) {
            float sv = X[c * HW + lane];
#pragma unroll
            for (int qq = 0; qq < 15; qq++)
                acc[qq] = fmaf(sv, qg[qq * CC + c], acc[qq]);
        }
    }
    __shared__ float part[4][15][52];
    if (lane < 52) {
#pragma unroll
        for (int qq = 0; qq < 15; qq++) part[wv][qq][lane] = (lane < HW) ? acc[qq] : 0.f;
    }
    __syncthreads();
    if (wv == 0) {
#pragma unroll
        for (int qq = 0; qq < 15; qq++) {
            float a = 0.f;
            if (lane < 52)
                a = part[0][qq][lane] + part[1][qq][lane] + part[2][qq][lane] + part[3][qq][lane];
            int q = qc * 15 + qq;
            float w = (lane < HW) ? (fmaxf(a, 0.f) + 1.01e-3f) : 0.f;
            float s = wsum64(w);
            if (lane < HW) ws[OFF_MARGB + ((b * QQ + q) * PP + p) * HW + lane] = w / s;
        }
    }
}

// ---------------- Kernel 4a: S-GEMM -> K, KT ----------------
// grid = 3000, block = 256. Computes S (cosine sim), writes K=exp(20S-20)
// row-major and KT row-major to ws, both with coalesced stores. Layout chosen
// so sinkhorn's per-lane row loads are lane-coalesced (kr from KT, kt from K).
__global__ __launch_bounds__(256) void gemm_kernel(const float* __restrict__ sup,
                                                   const float* __restrict__ qry,
                                                   float* __restrict__ ws) {
    __shared__ __align__(16) float AB[2][32][64];   // 16 KB staging; S_lds aliases it
    float (*S_lds)[53] = (float (*)[53])(&AB[0][0][0]);  // 50*53=2650 <= 4096 floats

    int prob = blockIdx.x;
    int p = prob % PP;
    int bq = prob / PP;
    int b = bq / QQ;
    int tid = threadIdx.x;
    int lane = tid & 63;
    int wv = tid >> 6;
    int tyc = tid / 13;
    int txc = tid - tyc * 13;
    bool active = tid < 169;

    const float* Xq = qry + (size_t)bq * CC * HW;
    const float* Xs = sup + (size_t)(b * PP + p) * CC * HW;

    float qm = 0.f, qi = 0.f, sm = 0.f, si = 0.f;
    if (lane < HW) {
        qm = ws[OFF_QMEAN + bq * HW + lane];
        qi = ws[OFF_QINV + bq * HW + lane];
        sm = ws[OFF_SMEAN + (b * PP + p) * HW + lane];
        si = ws[OFF_SINV + (b * PP + p) * HW + lane];
    }

    float acc[4][4];
#pragma unroll
    for (int i = 0; i < 4; i++)
#pragma unroll
        for (int j = 0; j < 4; j++) acc[i][j] = 0.f;

    for (int c0 = 0; c0 < CC; c0 += 32) {
        __syncthreads();
        for (int cl = wv; cl < 32; cl += 4) {
            int c = c0 + cl;
            float av = 0.f, bv = 0.f;
            if (lane < HW) {
                av = (Xq[c * HW + lane] - qm) * qi;
                bv = (Xs[c * HW + lane] - sm) * si;
            }
            AB[0][cl][lane] = av;
            AB[1][cl][lane] = bv;
        }
        __syncthreads();
        if (active) {
#pragma unroll
            for (int cl = 0; cl < 32; cl++) {
                float4 a4 = *(const float4*)&AB[0][cl][4 * tyc];
                float4 b4 = *(const float4*)&AB[1][cl][4 * txc];
                float av[4] = {a4.x, a4.y, a4.z, a4.w};
                float bv[4] = {b4.x, b4.y, b4.z, b4.w};
#pragma unroll
                for (int i = 0; i < 4; i++)
#pragma unroll
                    for (int j = 0; j < 4; j++) acc[i][j] = fmaf(av[i], bv[j], acc[i][j]);
            }
        }
    }

    __syncthreads();   // staging buffers dead; safe to overwrite with S
    if (active) {
#pragma unroll
        for (int i = 0; i < 4; i++) {
#pragma unroll
            for (int j = 0; j < 4; j++) {
                int m = 4 * tyc + i, n = 4 * txc + j;
                if (m < HW && n < HW) S_lds[m][n] = acc[i][j];
            }
        }
    }
    __syncthreads();

    // epilogue: K[m][n] = exp(20*S[m][n]-20); KT[m][n] = exp(20*S[n][m]-20).
    // Both stores coalesced; transposed LDS read has stride 53 (odd) = conflict-free.
    float* Kp = ws + OFF_K + (size_t)prob * HW2;
    float* KTp = ws + OFF_KT + (size_t)prob * HW2;
    for (int idx = tid; idx < HW2; idx += 256) {
        int m = idx / HW;
        int n = idx - m * HW;
        Kp[idx] = __expf(fmaf(20.f, S_lds[m][n], -20.f));
        KTp[idx] = __expf(fmaf(20.f, S_lds[n][m], -20.f));
    }
}

// ---------------- Kernel 4b: Sinkhorn + logit, one wave per problem ----------
// 64-thread blocks, ZERO LDS -> residency is register-bound only (~3 waves/SIMD
// = 12 concurrent problems/CU vs ~3.5 in the fused version). K row/col pinned
// in AGPRs via asm ("a"); reads are volatile ONLY to stop LICM hoisting them
// into 98 VGPRs (writes are non-volatile so the scheduler stays free).
#define AGPR_W(av, x) asm("v_accvgpr_write_b32 %0, %1" : "=a"(av) : "v"(x))
#define AGPR_RV(x, av) asm volatile("v_accvgpr_read_b32 %0, %1" : "=v"(x) : "a"(av))

#define KL(X) X(0) X(1) X(2) X(3) X(4) X(5) X(6) X(7) X(8) X(9) X(10) X(11) \
    X(12) X(13) X(14) X(15) X(16) X(17) X(18) X(19) X(20) X(21) X(22) X(23) \
    X(24) X(25) X(26) X(27) X(28) X(29) X(30) X(31) X(32) X(33) X(34) X(35) \
    X(36) X(37) X(38) X(39) X(40) X(41) X(42) X(43) X(44) X(45) X(46) X(47) X(48)

__global__ __launch_bounds__(64) void sinkhorn_kernel(float* __restrict__ ws) {
    int prob = blockIdx.x;
    int lane = threadIdx.x;
    const float* Kp = ws + OFF_K + (size_t)prob * HW2;
    const float* KTp = ws + OFF_KT + (size_t)prob * HW2;

    float am = 0.f, bm = 0.f;
    if (lane < HW) {
        am = ws[OFF_MARGA + prob * HW + lane];
        bm = ws[OFF_MARGB + prob * HW + lane];
    }
    int ll = (lane < HW) ? lane : 48;   // clamp inactive lanes in-bounds

    // kr_n = K[lane][n] = KT[n][lane]  -> load KTp[n*49+lane]  (lane-coalesced)
    // kt_m = KT[lane][m] = K[m][lane]  -> load Kp[m*49+lane]   (lane-coalesced)
#define KD(n) float kr##n, kt##n;
    KL(KD)
#undef KD
#define KI(n) { float a_ = KTp[(n) * HW + ll]; float b_ = Kp[(n) * HW + ll]; \
                AGPR_W(kr##n, a_); AGPR_W(kt##n, b_); }
    KL(KI)
#undef KI

    float vv = (lane < HW) ? 1.f : 0.f;
    float uu = 0.f;

#pragma unroll 1
    for (int it = 0; it < 100; it++) {
        // u = a / (K v): t_m = sum_n kr_n * v_n  (v broadcast via readlane)
        float a4[4] = {0.f, 0.f, 0.f, 0.f};
#define UM(n) { float kv; AGPR_RV(kv, kr##n);                               \
                a4[(n) & 3] = fmaf(rlf(vv, (n)), kv, a4[(n) & 3]); }
        KL(UM)
#undef UM
        float t = (a4[0] + a4[1]) + (a4[2] + a4[3]);
        uu = am * __builtin_amdgcn_rcpf(t);
        // v = b / (K^T u): s_n = sum_m kt_m * u_m
        float b4[4] = {0.f, 0.f, 0.f, 0.f};
#define VM(n) { float kv; AGPR_RV(kv, kt##n);                               \
                b4[(n) & 3] = fmaf(rlf(uu, (n)), kv, b4[(n) & 3]); }
        KL(VM)
#undef VM
        float s = (b4[0] + b4[1]) + (b4[2] + b4[3]);
        vv = bm * __builtin_amdgcn_rcpf(s);
    }

    // logit = T * sum_{m,n} S*P, with S = 1 + 0.05*ln(K) (K = exp(20S-20))
    float ssum = 0.f;
#define FS(n) { float kv; AGPR_RV(kv, kr##n);                               \
                float sv = fmaf(0.05f, __logf(kv), 1.0f);                   \
                ssum = fmaf(kv * sv, rlf(vv, (n)), ssum); }
    KL(FS)
#undef FS
    float contrib = (lane < HW) ? (uu * ssum) : 0.f;
    float tot = wsum64(contrib);
    if (lane == 0) ws[OFF_LOGITS + prob] = TEMP * tot;
}

// ---------------- Kernel 5: cross-entropy loss ----------------
__global__ __launch_bounds__(640) void loss_kernel(const float* __restrict__ ws,
                                                   const int* __restrict__ qy,
                                                   float* __restrict__ out) {
    int tid = threadIdx.x;
    float val = 0.f;
    if (tid < NIMG_Q) {
        const float* lg = ws + OFF_LOGITS + tid * PP;
        float l[PP];
        float mx = -1e30f;
#pragma unroll
        for (int p = 0; p < PP; p++) {
            l[p] = lg[p];
            mx = fmaxf(mx, l[p]);
        }
        float se = 0.f;
#pragma unroll
        for (int p = 0; p < PP; p++) se += __expf(l[p] - mx);
        float lse = mx + logf(se);
        int lab = qy[tid];
        val = -(l[lab] - lse);
    }
    __shared__ float red[16];
    float s = wsum64(val);
    if ((tid & 63) == 0) red[tid >> 6] = s;
    __syncthreads();
    if (tid == 0) {
        float tot = 0.f;
#pragma unroll
        for (int w = 0; w < 10; w++) tot += red[w];
        out[0] = tot * (1.0f / NIMG_Q);
    }
}

extern "C" void kernel_launch(void* const* d_in, const int* in_sizes, int n_in,
                              void* d_out, int out_size, void* d_ws, size_t ws_size,
                              hipStream_t stream) {
    const float* sup = (const float*)d_in[0];   // support_xf [8,5,640,7,7]
    const float* qry = (const float*)d_in[1];   // query_xf   [8,75,640,7,7]
    const int* qy = (const int*)d_in[3];        // query_y    [8,75]
    float* ws = (float*)d_ws;
    float* out = (float*)d_out;

    sup_stats_kernel<<<NIMG_S, 256, 0, stream>>>(sup, ws);
    qry_kernel<<<NIMG_Q, 256, 0, stream>>>(qry, ws);
    margb_kernel<<<NIMG_S * 5, 256, 0, stream>>>(sup, ws);
    gemm_kernel<<<NPROB, 256, 0, stream>>>(sup, qry, ws);
    sinkhorn_kernel<<<NPROB, 64, 0, stream>>>(ws);
    loss_kernel<<<1, 640, 0, stream>>>(ws, qy, out);
}

// Round 6
// 468.927 us; speedup vs baseline: 1.9006x; 1.3393x over previous
//
#include <hip/hip_runtime.h>
#include <math.h>

#define BB 8
#define PP 5
#define QQ 75
#define CC 640
#define HW 49
#define HW2 (HW*HW)        // 2401
#define NIMG_Q (BB*QQ)     // 600
#define NIMG_S (BB*PP)     // 40
#define NPROB  (BB*QQ*PP)  // 3000
#define TEMP 12.5f

// workspace layout (float offsets)
#define OFF_SGAP   0
#define OFF_QGAP   (OFF_SGAP  + NIMG_S*CC)
#define OFF_SMEAN  (OFF_QGAP  + NIMG_Q*CC)
#define OFF_SINV   (OFF_SMEAN + NIMG_S*HW)
#define OFF_QMEAN  (OFF_SINV  + NIMG_S*HW)
#define OFF_QINV   (OFF_QMEAN + NIMG_Q*HW)
#define OFF_MARGA  (OFF_QINV  + NIMG_Q*HW)
#define OFF_MARGB  (OFF_MARGA + NPROB*HW)
#define OFF_K      (OFF_MARGB + NPROB*HW)
#define OFF_KT     (OFF_K     + NPROB*HW2)
#define OFF_LOGITS (OFF_KT    + NPROB*HW2)

typedef short bf16x8 __attribute__((ext_vector_type(8)));
typedef float f32x4 __attribute__((ext_vector_type(4)));
#define MFMA16 __builtin_amdgcn_mfma_f32_16x16x32_bf16

__device__ __forceinline__ float wsum64(float v) {
#pragma unroll
    for (int off = 32; off > 0; off >>= 1) v += __shfl_xor(v, off, 64);
    return v;
}

__device__ __forceinline__ float rlf(float x, int l) {
    return __int_as_float(__builtin_amdgcn_readlane(__float_as_int(x), l));
}

// float -> bf16 bits (RNE) and back
__device__ __forceinline__ unsigned short bfb(float x) {
    unsigned u = __float_as_uint(x);
    return (unsigned short)((u + 0x7FFFu + ((u >> 16) & 1u)) >> 16);
}
__device__ __forceinline__ float bfu(unsigned short h) {
    return __uint_as_float(((unsigned)h) << 16);
}

// ---------------- Kernel 1: support-image stats ----------------
__global__ __launch_bounds__(256) void sup_stats_kernel(const float* __restrict__ sup,
                                                        float* __restrict__ ws) {
    int img = blockIdx.x;
    int tid = threadIdx.x;
    int lane = tid & 63;
    int wv = tid >> 6;
    const float* X = sup + (size_t)img * CC * HW;
    float* gap = ws + OFF_SGAP + img * CC;
    float* cmean = ws + OFF_SMEAN + img * HW;
    float* cinv = ws + OFF_SINV + img * HW;

    __shared__ float cs_p[4][52], sq_p[4][52];
    float cs = 0.f, sq = 0.f;
    if (lane < HW) {
        for (int c = wv * 160; c < wv * 160 + 160; c++) {
            float v = X[c * HW + lane];
            cs += v;
            sq = fmaf(v, v, sq);
        }
    }
    if (lane < 52) {
        cs_p[wv][lane] = (lane < HW) ? cs : 0.f;
        sq_p[wv][lane] = (lane < HW) ? sq : 0.f;
    }
    __syncthreads();
    if (wv == 0 && lane < HW) {
        float c4 = cs_p[0][lane] + cs_p[1][lane] + cs_p[2][lane] + cs_p[3][lane];
        float s4 = sq_p[0][lane] + sq_p[1][lane] + sq_p[2][lane] + sq_p[3][lane];
        float mu = c4 * (1.0f / CC);
        float nsq = fmaxf(s4 - c4 * c4 * (1.0f / CC), 0.f);
        cmean[lane] = mu;
        cinv[lane] = 1.0f / fmaxf(sqrtf(nsq), 1e-8f);
    }
    for (int c = tid; c < CC; c += 256) {
        float s = 0.f;
        for (int m = 0; m < HW; m++) s += X[c * HW + m];
        gap[c] = s * (1.0f / HW);
    }
}

// ---------------- Kernel 2: query stats + marga fused ----------------
__global__ __launch_bounds__(256) void qry_kernel(const float* __restrict__ qry,
                                                  float* __restrict__ ws) {
    int img = blockIdx.x;            // = bq
    int b = img / QQ;
    int tid = threadIdx.x;
    int lane = tid & 63;
    int wv = tid >> 6;
    const float* X = qry + (size_t)img * CC * HW;
    const float* sg = ws + OFF_SGAP + b * PP * CC;
    float* gap = ws + OFF_QGAP + img * CC;
    float* cmean = ws + OFF_QMEAN + img * HW;
    float* cinv = ws + OFF_QINV + img * HW;

    __shared__ float cs_p[4][52], sq_p[4][52];
    __shared__ float part[4][PP][52];
    float cs = 0.f, sq = 0.f;
    float acc[PP] = {0.f, 0.f, 0.f, 0.f, 0.f};
    if (lane < HW) {
        for (int c = wv * 160; c < wv * 160 + 160; c++) {
            float v = X[c * HW + lane];
            cs += v;
            sq = fmaf(v, v, sq);
#pragma unroll
            for (int p = 0; p < PP; p++) acc[p] = fmaf(v, sg[p * CC + c], acc[p]);
        }
    }
    if (lane < 52) {
        cs_p[wv][lane] = (lane < HW) ? cs : 0.f;
        sq_p[wv][lane] = (lane < HW) ? sq : 0.f;
#pragma unroll
        for (int p = 0; p < PP; p++) part[wv][p][lane] = (lane < HW) ? acc[p] : 0.f;
    }
    __syncthreads();
    if (wv == 0) {
        if (lane < HW) {
            float c4 = cs_p[0][lane] + cs_p[1][lane] + cs_p[2][lane] + cs_p[3][lane];
            float s4 = sq_p[0][lane] + sq_p[1][lane] + sq_p[2][lane] + sq_p[3][lane];
            float mu = c4 * (1.0f / CC);
            float nsq = fmaxf(s4 - c4 * c4 * (1.0f / CC), 0.f);
            cmean[lane] = mu;
            cinv[lane] = 1.0f / fmaxf(sqrtf(nsq), 1e-8f);
        }
#pragma unroll
        for (int p = 0; p < PP; p++) {
            float a = 0.f;
            if (lane < 52)
                a = part[0][p][lane] + part[1][p][lane] + part[2][p][lane] + part[3][p][lane];
            float w = (lane < HW) ? (fmaxf(a, 0.f) + 1.01e-3f) : 0.f;
            float s = wsum64(w);
            if (lane < HW) ws[OFF_MARGA + (img * PP + p) * HW + lane] = w / s;
        }
    }
    for (int c = tid; c < CC; c += 256) {
        float s = 0.f;
        for (int m = 0; m < HW; m++) s += X[c * HW + m];
        gap[c] = s * (1.0f / HW);
    }
}

// ---------------- Kernel 3: col marginals b (support side, w2) ----------------
__global__ __launch_bounds__(256) void margb_kernel(const float* __restrict__ sup,
                                                    float* __restrict__ ws) {
    int id = blockIdx.x;
    int qc = id % 5;
    int bp = id / 5;
    int b = bp / PP;
    int p = bp % PP;
    int tid = threadIdx.x;
    int lane = tid & 63;
    int wv = tid >> 6;
    const float* X = sup + (size_t)bp * CC * HW;
    const float* qg = ws + OFF_QGAP + (b * QQ + qc * 15) * CC;
    float acc[15];
#pragma unroll
    for (int i = 0; i < 15; i++) acc[i] = 0.f;
    if (lane < HW) {
        for (int c = wv * 160; c < wv * 160 + 160; c++) {
            float sv = X[c * HW + lane];
#pragma unroll
            for (int qq = 0; qq < 15; qq++)
                acc[qq] = fmaf(sv, qg[qq * CC + c], acc[qq]);
        }
    }
    __shared__ float part[4][15][52];
    if (lane < 52) {
#pragma unroll
        for (int qq = 0; qq < 15; qq++) part[wv][qq][lane] = (lane < HW) ? acc[qq] : 0.f;
    }
    __syncthreads();
    if (wv == 0) {
#pragma unroll
        for (int qq = 0; qq < 15; qq++) {
            float a = 0.f;
            if (lane < 52)
                a = part[0][qq][lane] + part[1][qq][lane] + part[2][qq][lane] + part[3][qq][lane];
            int q = qc * 15 + qq;
            float w = (lane < HW) ? (fmaxf(a, 0.f) + 1.01e-3f) : 0.f;
            float s = wsum64(w);
            if (lane < HW) ws[OFF_MARGB + ((b * QQ + q) * PP + p) * HW + lane] = w / s;
        }
    }
}

// ---------------- Kernel 4a: MFMA S-GEMM (bf16x3) -> K, KT ----------------
// grid = 3000, block = 256 (4 waves). S = Ah*Bh + Ah*Bl + Al*Bh with A,B split
// into bf16 hi/lo (error ~1e-5, harmless under exp(20S-20)). LDS holds
// row-major bf16 operand tiles so each MFMA fragment is ONE ds_read_b128
// (f32 outer-product version was LDS-pipe-bound: 61K LDS-cyc/block -> ~13K).
__global__ __launch_bounds__(256) void gemm_kernel(const float* __restrict__ sup,
                                                   const float* __restrict__ qry,
                                                   float* __restrict__ ws) {
    // row stride 20 u32 = 80 B: 16B-aligned for b128, odd-ish banking (2-way max)
    __shared__ unsigned AhB[64 * 20], AlB[64 * 20], BhB[64 * 20], BlB[64 * 20];
    __shared__ float S_lds[50 * 53];

    int prob = blockIdx.x;
    int p = prob % PP;
    int bq = prob / PP;
    int b = bq / QQ;
    int tid = threadIdx.x;
    int lane = tid & 63;
    int wv = tid >> 6;
    int rw = lane;               // staging row (m for A, n for B)
    int cg = tid >> 6;           // staging c-group 0..3
    int lrow = lane & 15;        // fragment row within 16-tile
    int quad = lane >> 4;

    const float* Xq = qry + (size_t)bq * CC * HW;
    const float* Xs = sup + (size_t)(b * PP + p) * CC * HW;

    float qm = 0.f, qi = 0.f, smv = 0.f, siv = 0.f;
    if (lane < HW) {
        qm = ws[OFF_QMEAN + bq * HW + lane];
        qi = ws[OFF_QINV + bq * HW + lane];
        smv = ws[OFF_SMEAN + (b * PP + p) * HW + lane];
        siv = ws[OFF_SINV + (b * PP + p) * HW + lane];
    }

    f32x4 acc[4];
#pragma unroll
    for (int nt = 0; nt < 4; nt++) acc[nt] = (f32x4){0.f, 0.f, 0.f, 0.f};

    for (int c0 = 0; c0 < CC; c0 += 32) {
        __syncthreads();
        // stage: thread handles 4 c-pairs (8 c's) for its row rw, both operands
#pragma unroll
        for (int pr = 0; pr < 4; pr++) {
            int cl = cg * 8 + pr * 2;
            int c = c0 + cl;
            float a0 = 0.f, a1 = 0.f, b0 = 0.f, b1 = 0.f;
            if (rw < HW) {
                a0 = (Xq[c * HW + rw] - qm) * qi;
                a1 = (Xq[(c + 1) * HW + rw] - qm) * qi;
                b0 = (Xs[c * HW + rw] - smv) * siv;
                b1 = (Xs[(c + 1) * HW + rw] - smv) * siv;
            }
            unsigned short ah0 = bfb(a0), ah1 = bfb(a1);
            unsigned short bh0 = bfb(b0), bh1 = bfb(b1);
            unsigned short al0 = bfb(a0 - bfu(ah0)), al1 = bfb(a1 - bfu(ah1));
            unsigned short bl0 = bfb(b0 - bfu(bh0)), bl1 = bfb(b1 - bfu(bh1));
            int o = rw * 20 + (cl >> 1);
            AhB[o] = ((unsigned)ah1 << 16) | ah0;
            AlB[o] = ((unsigned)al1 << 16) | al0;
            BhB[o] = ((unsigned)bh1 << 16) | bh0;
            BlB[o] = ((unsigned)bl1 << 16) | bl0;
        }
        __syncthreads();
        // compute: wave wv owns m-tile wv (rows 16wv..16wv+16), all 4 n-tiles
        int aoff = (16 * wv + lrow) * 20 + quad * 4;
        bf16x8 ah = *(const bf16x8*)&AhB[aoff];
        bf16x8 al = *(const bf16x8*)&AlB[aoff];
#pragma unroll
        for (int nt = 0; nt < 4; nt++) {
            int boff = (16 * nt + lrow) * 20 + quad * 4;
            bf16x8 bh = *(const bf16x8*)&BhB[boff];
            bf16x8 bl = *(const bf16x8*)&BlB[boff];
            acc[nt] = MFMA16(ah, bh, acc[nt], 0, 0, 0);
            acc[nt] = MFMA16(ah, bl, acc[nt], 0, 0, 0);
            acc[nt] = MFMA16(al, bh, acc[nt], 0, 0, 0);
        }
    }

    // acc -> S_lds. C/D layout: col = lane&15, row = quad*4 + reg (verified m89)
#pragma unroll
    for (int nt = 0; nt < 4; nt++) {
#pragma unroll
        for (int r = 0; r < 4; r++) {
            int mm = 16 * wv + quad * 4 + r;
            int nn = 16 * nt + lrow;
            if (mm < HW && nn < HW) S_lds[mm * 53 + nn] = acc[nt][r];
        }
    }
    __syncthreads();

    // epilogue: K = exp(20S-20) row-major, KT row-major, coalesced stores
    float* Kp = ws + OFF_K + (size_t)prob * HW2;
    float* KTp = ws + OFF_KT + (size_t)prob * HW2;
    for (int idx = tid; idx < HW2; idx += 256) {
        int m = idx / HW;
        int n = idx - m * HW;
        Kp[idx] = __expf(fmaf(20.f, S_lds[m * 53 + n], -20.f));
        KTp[idx] = __expf(fmaf(20.f, S_lds[n * 53 + m], -20.f));
    }
}

// ---------------- Kernel 4b: Sinkhorn + logit, one wave per problem ----------
// K rows/cols in plain named float4 registers. waves_per_eu(3,3) sets the
// VGPR budget to ~170 (the default occupancy heuristic capped at ~84 and
// spilled in R1-R3; the asm-AGPR workaround in R5 serialized at ~310
// instrs/iter). Loop body is pure VALU: readlane broadcast + fma.
#define FOR12(M) M(0) M(1) M(2) M(3) M(4) M(5) M(6) M(7) M(8) M(9) M(10) M(11)

__global__ __launch_bounds__(64)
__attribute__((amdgpu_waves_per_eu(3, 3)))
void sinkhorn_kernel(float* __restrict__ ws) {
    int prob = blockIdx.x;
    int lane = threadIdx.x;
    const float* Kp = ws + OFF_K + (size_t)prob * HW2;
    const float* KTp = ws + OFF_KT + (size_t)prob * HW2;

    float am = 0.f, bm = 0.f;
    if (lane < HW) {
        am = ws[OFF_MARGA + prob * HW + lane];
        bm = ws[OFF_MARGB + prob * HW + lane];
    }
    int ll = (lane < HW) ? lane : 48;   // clamp inactive lanes in-bounds

    // kr_n = K[lane][n] = KT[n][lane]; kt_n = KT[lane][n] = K[n][lane]
    float4 kr0, kr1, kr2, kr3, kr4, kr5, kr6, kr7, kr8, kr9, kr10, kr11, kr12;
    float4 kt0, kt1, kt2, kt3, kt4, kt5, kt6, kt7, kt8, kt9, kt10, kt11, kt12;
#define KI(g)                                                               \
    kr##g = make_float4(KTp[(4*(g)+0)*HW + ll], KTp[(4*(g)+1)*HW + ll],     \
                        KTp[(4*(g)+2)*HW + ll], KTp[(4*(g)+3)*HW + ll]);    \
    kt##g = make_float4(Kp[(4*(g)+0)*HW + ll], Kp[(4*(g)+1)*HW + ll],       \
                        Kp[(4*(g)+2)*HW + ll], Kp[(4*(g)+3)*HW + ll]);
    FOR12(KI)
#undef KI
    kr12 = make_float4(KTp[48 * HW + ll], 0.f, 0.f, 0.f);
    kt12 = make_float4(Kp[48 * HW + ll], 0.f, 0.f, 0.f);

    float vv = (lane < HW) ? 1.f : 0.f;
    float uu = 0.f;

#pragma unroll 1
    for (int it = 0; it < 100; it++) {
        float t0 = 0.f, t1 = 0.f, t2 = 0.f, t3 = 0.f;
#define RS(g) { t0 = fmaf(kr##g.x, rlf(vv, 4*(g)+0), t0);                   \
                t1 = fmaf(kr##g.y, rlf(vv, 4*(g)+1), t1);                   \
                t2 = fmaf(kr##g.z, rlf(vv, 4*(g)+2), t2);                   \
                t3 = fmaf(kr##g.w, rlf(vv, 4*(g)+3), t3); }
        FOR12(RS)
#undef RS
        t0 = fmaf(kr12.x, rlf(vv, 48), t0);
        float t = (t0 + t1) + (t2 + t3);
        uu = am * __builtin_amdgcn_rcpf(t);

        float s0 = 0.f, s1 = 0.f, s2 = 0.f, s3 = 0.f;
#define CS(g) { s0 = fmaf(kt##g.x, rlf(uu, 4*(g)+0), s0);                   \
                s1 = fmaf(kt##g.y, rlf(uu, 4*(g)+1), s1);                   \
                s2 = fmaf(kt##g.z, rlf(uu, 4*(g)+2), s2);                   \
                s3 = fmaf(kt##g.w, rlf(uu, 4*(g)+3), s3); }
        FOR12(CS)
#undef CS
        s0 = fmaf(kt12.x, rlf(uu, 48), s0);
        float s = (s0 + s1) + (s2 + s3);
        vv = bm * __builtin_amdgcn_rcpf(s);
    }

    // logit = T * sum S*P with S = 1 + 0.05*ln(K)
    float ssum = 0.f;
#define FS(g) {                                                             \
    ssum = fmaf(kr##g.x * fmaf(0.05f, __logf(kr##g.x), 1.f), rlf(vv, 4*(g)+0), ssum); \
    ssum = fmaf(kr##g.y * fmaf(0.05f, __logf(kr##g.y), 1.f), rlf(vv, 4*(g)+1), ssum); \
    ssum = fmaf(kr##g.z * fmaf(0.05f, __logf(kr##g.z), 1.f), rlf(vv, 4*(g)+2), ssum); \
    ssum = fmaf(kr##g.w * fmaf(0.05f, __logf(kr##g.w), 1.f), rlf(vv, 4*(g)+3), ssum); }
    FOR12(FS)
#undef FS
    ssum = fmaf(kr12.x * fmaf(0.05f, __logf(kr12.x), 1.f), rlf(vv, 48), ssum);
    float contrib = (lane < HW) ? (uu * ssum) : 0.f;
    float tot = wsum64(contrib);
    if (lane == 0) ws[OFF_LOGITS + prob] = TEMP * tot;
}

// ---------------- Kernel 5: cross-entropy loss ----------------
__global__ __launch_bounds__(640) void loss_kernel(const float* __restrict__ ws,
                                                   const int* __restrict__ qy,
                                                   float* __restrict__ out) {
    int tid = threadIdx.x;
    float val = 0.f;
    if (tid < NIMG_Q) {
        const float* lg = ws + OFF_LOGITS + tid * PP;
        float l[PP];
        float mx = -1e30f;
#pragma unroll
        for (int p = 0; p < PP; p++) {
            l[p] = lg[p];
            mx = fmaxf(mx, l[p]);
        }
        float se = 0.f;
#pragma unroll
        for (int p = 0; p < PP; p++) se += __expf(l[p] - mx);
        float lse = mx + logf(se);
        int lab = qy[tid];
        val = -(l[lab] - lse);
    }
    __shared__ float red[16];
    float s = wsum64(val);
    if ((tid & 63) == 0) red[tid >> 6] = s;
    __syncthreads();
    if (tid == 0) {
        float tot = 0.f;
#pragma unroll
        for (int w = 0; w < 10; w++) tot += red[w];
        out[0] = tot * (1.0f / NIMG_Q);
    }
}

extern "C" void kernel_launch(void* const* d_in, const int* in_sizes, int n_in,
                              void* d_out, int out_size, void* d_ws, size_t ws_size,
                              hipStream_t stream) {
    const float* sup = (const float*)d_in[0];   // support_xf [8,5,640,7,7]
    const float* qry = (const float*)d_in[1];   // query_xf   [8,75,640,7,7]
    const int* qy = (const int*)d_in[3];        // query_y    [8,75]
    float* ws = (float*)d_ws;
    float* out = (float*)d_out;

    sup_stats_kernel<<<NIMG_S, 256, 0, stream>>>(sup, ws);
    qry_kernel<<<NIMG_Q, 256, 0, stream>>>(qry, ws);
    margb_kernel<<<NIMG_S * 5, 256, 0, stream>>>(sup, ws);
    gemm_kernel<<<NPROB, 256, 0, stream>>>(sup, qry, ws);
    sinkhorn_kernel<<<NPROB, 64, 0, stream>>>(ws);
    loss_kernel<<<1, 640, 0, stream>>>(ws, qy, out);
}